// Round 7
// baseline (83.730 us; speedup 1.0000x reference)
//
#include <hip/hip_runtime.h>

#define B_ROWS 8192
#define IN_DIM 2048
#define D_DIM  1024
#define C_CLS  1000

typedef __attribute__((ext_vector_type(8))) short   bf16x8;
typedef __attribute__((ext_vector_type(4))) float   f32x4;

__device__ __forceinline__ unsigned short f2b(float f) {
    unsigned int u = __builtin_bit_cast(unsigned int, f);
    u = u + 0x7fffu + ((u >> 16) & 1u);   // RNE
    return (unsigned short)(u >> 16);
}
__device__ __forceinline__ void g2lds16(const void* g, void* l) {
    __builtin_amdgcn_global_load_lds(
        (const __attribute__((address_space(1))) unsigned int*)g,
        (__attribute__((address_space(3))) unsigned int*)l,
        16, 0, 0);
}

// ---------------- fused prep, one launch:
//   blocks [0,2048):      W[2048][1024] f32 -> Wt[1024][2048] bf16 (transpose+cvt)
//   blocks [2048,3072):   prototypes -> Pb bf16 (rows >=1000 zeroed) + p2
//   blocks [3072,11264):  x f32 -> xb bf16 (8 elems/thread)
__global__ __launch_bounds__(256) void k_pre(const float* __restrict__ W,
                                             const float* __restrict__ P,
                                             const float* __restrict__ x,
                                             unsigned short* __restrict__ Wt,
                                             unsigned short* __restrict__ Pb,
                                             unsigned short* __restrict__ xb,
                                             float* __restrict__ p2) {
    const int tid = threadIdx.x;
    if (blockIdx.x >= 3072) {
        const size_t i = (((size_t)blockIdx.x - 3072) * 256 + tid) * 8;
        float4 v0 = *(const float4*)(x + i);
        float4 v1 = *(const float4*)(x + i + 4);
        bf16x8 h;
        h[0] = (short)f2b(v0.x); h[1] = (short)f2b(v0.y);
        h[2] = (short)f2b(v0.z); h[3] = (short)f2b(v0.w);
        h[4] = (short)f2b(v1.x); h[5] = (short)f2b(v1.y);
        h[6] = (short)f2b(v1.z); h[7] = (short)f2b(v1.w);
        *(bf16x8*)(xb + i) = h;
    } else if (blockIdx.x < 2048) {
        __shared__ float t[32][33];
        const int tx = tid & 31, ty = tid >> 5;           // 32 x 8
        const int kb = (blockIdx.x & 63) * 32;            // K (2048/32=64)
        const int nb = (blockIdx.x >> 6) * 32;            // N (1024/32=32)
#pragma unroll
        for (int j = 0; j < 4; ++j)
            t[ty + 8 * j][tx] = W[(size_t)(kb + ty + 8 * j) * D_DIM + nb + tx];
        __syncthreads();
#pragma unroll
        for (int j = 0; j < 4; ++j)
            Wt[(size_t)(nb + ty + 8 * j) * IN_DIM + kb + tx] = f2b(t[tx][ty + 8 * j]);
    } else {
        const int c = blockIdx.x - 2048;   // 0..1023
        float s = 0.f;
        if (c < C_CLS) {
            float4 v = *((const float4*)(P + (size_t)c * D_DIM) + tid);
            s = v.x * v.x + v.y * v.y + v.z * v.z + v.w * v.w;
            ushort4 h; h.x = f2b(v.x); h.y = f2b(v.y); h.z = f2b(v.z); h.w = f2b(v.w);
            *((ushort4*)(Pb + (size_t)c * D_DIM) + tid) = h;
        } else {
            ushort4 h; h.x = 0; h.y = 0; h.z = 0; h.w = 0;
            *((ushort4*)(Pb + (size_t)c * D_DIM) + tid) = h;
        }
#pragma unroll
        for (int o = 32; o > 0; o >>= 1) s += __shfl_down(s, o);
        __shared__ float red[4];
        if ((tid & 63) == 0) red[tid >> 6] = s;
        __syncthreads();
        if (tid == 0) p2[c] = red[0] + red[1] + red[2] + red[3];
    }
}

// ---------------- 8-phase deep-pipelined GEMM: tile 256x128, BK=64, 512 thr
// (8 waves 4Mx2N, 64x64 each). 3-stage LDS, counted vmcnt(6) ONLY at tile
// boundary. Per K-tile: 4 quadrant phases (gray code), each
// {ds_read quadrant || issue 2 global_load_lds(t+2) || barrier || 8 MFMA || barrier}.
// MODE 0: Zb = xb @ Wt^T + bias (bf16 out) + z2 partials.   K = 2048
// MODE 1: Out = (2*(Zb @ Pb^T) - z2 - p2)/1024.             K = 1024
template <int MODE>
__global__ __launch_bounds__(512, 2) void k_gemm8(
    const unsigned short* __restrict__ Ab,    // [M][K] bf16
    const unsigned short* __restrict__ Bt,    // [N][K] bf16
    const float* __restrict__ bias,
    const float* __restrict__ z2p_in,         // MODE1: [16][8192]
    const float* __restrict__ p2,
    unsigned short* __restrict__ Zout,
    float* __restrict__ z2p_out,
    float* __restrict__ Out) {
    constexpr int K  = (MODE == 0) ? IN_DIM : D_DIM;
    constexpr int NT = K / 64;
    constexpr unsigned ASZ = 256 * 64 * 2;    // 32 KB / stage
    constexpr unsigned BSZ = 128 * 64 * 2;    // 16 KB / stage
    extern __shared__ char lds[];
    char* pa0 = lds;            char* pa1 = lds + ASZ;  char* pa2 = lds + 2 * ASZ;
    char* pb0 = lds + 3 * ASZ;  char* pb1 = pb0 + BSZ;  char* pb2 = pb0 + 2 * BSZ;
    float* z2loc = (float*)(lds + 3 * (ASZ + BSZ));     // 1 KB (MODE1)

    const int tid  = threadIdx.x;
    const int wave = tid >> 6, lane = tid & 63;
    const int lo = lane & 15, hi = lane >> 4;
    const int wm = wave >> 1, wn = wave & 1;   // 4M x 2N waves, 64x64 each

    const int swz = ((blockIdx.x & 7) << 5) + (blockIdx.x >> 3);
    const int bm = swz >> 3, bn = swz & 7;     // 32 x 8
    const int rowbase = bm * 256, colbase = bn * 128;

    const int srow   = lane >> 3;
    const int gchunk = (lane & 7) ^ (srow & 7);   // pre-XOR'd source, linear LDS dest

    auto STAGE_A = [&](char* dst, int kt, int i) {   // i 0..3 (32 segs / 8 waves)
        const int s = i * 8 + wave;
        g2lds16(Ab + (size_t)(rowbase + s * 8 + srow) * K + kt * 64 + gchunk * 8,
                dst + s * 1024);
    };
    auto STAGE_B = [&](char* dst, int kt, int i) {   // i 0..1 (16 segs / 8 waves)
        const int s = i * 8 + wave;
        g2lds16(Bt + (size_t)(colbase + s * 8 + srow) * K + kt * 64 + gchunk * 8,
                dst + s * 1024);
    };

    f32x4 acc[4][4];
#pragma unroll
    for (int m = 0; m < 4; ++m)
#pragma unroll
        for (int n = 0; n < 4; ++n) acc[m][n] = (f32x4){0.f, 0.f, 0.f, 0.f};

    // ---- prologue: z2 partial reduce (MODE1), stage tiles 0+1, wait tile 0
    if constexpr (MODE == 1) {
        if (tid < 256) {
            float s = 0.f;
#pragma unroll
            for (int j = 0; j < 16; ++j) s += z2p_in[j * B_ROWS + rowbase + tid];
            z2loc[tid] = s;
        }
    }
#pragma unroll
    for (int i = 0; i < 4; ++i) STAGE_A(pa0, 0, i);
    STAGE_B(pb0, 0, 0); STAGE_B(pb0, 0, 1);
#pragma unroll
    for (int i = 0; i < 4; ++i) STAGE_A(pa1, 1, i);
    STAGE_B(pb1, 1, 0); STAGE_B(pb1, 1, 1);
    asm volatile("s_waitcnt vmcnt(6) lgkmcnt(0)" ::: "memory");
    __builtin_amdgcn_s_barrier();

    auto RD_A = [&](int mrow, int ks) -> bf16x8 {     // mrow 0..3
        const int row = wm * 64 + mrow * 16 + lo;
        unsigned addr = (unsigned)(row * 128 + ks * 64 + hi * 16)
                      ^ (unsigned)((lo & 7) << 4);
        return *(const bf16x8*)(pa0 + addr);
    };
    auto RD_B = [&](int nrow, int ks) -> bf16x8 {     // nrow 0..3
        const int row = wn * 64 + nrow * 16 + lo;
        unsigned addr = (unsigned)(row * 128 + ks * 64 + hi * 16)
                      ^ (unsigned)((lo & 7) << 4);
        return *(const bf16x8*)(pb0 + addr);
    };

    // ---- main loop: 4 gray-code quadrant phases per K-tile
    for (int t = 0; t < NT; ++t) {
        const bool stg = (t < NT - 2);
        bf16x8 a0k0, a0k1, a1k0, a1k1;   // A frags for current mh
        bf16x8 b0k0, b0k1, b1k0, b1k1;   // B frags for current nh

        // ===== phase 0: (mh=0, nh=0) — load A-half0 + B-half0
        a0k0 = RD_A(0, 0); a0k1 = RD_A(0, 1);
        a1k0 = RD_A(1, 0); a1k1 = RD_A(1, 1);
        b0k0 = RD_B(0, 0); b0k1 = RD_B(0, 1);
        b1k0 = RD_B(1, 0); b1k1 = RD_B(1, 1);
        if (stg) { STAGE_A(pa2, t + 2, 0); STAGE_A(pa2, t + 2, 1); }
        __builtin_amdgcn_s_barrier();
        __builtin_amdgcn_s_setprio(1);
        acc[0][0] = __builtin_amdgcn_mfma_f32_16x16x32_bf16(a0k0, b0k0, acc[0][0], 0, 0, 0);
        acc[0][1] = __builtin_amdgcn_mfma_f32_16x16x32_bf16(a0k0, b1k0, acc[0][1], 0, 0, 0);
        acc[1][0] = __builtin_amdgcn_mfma_f32_16x16x32_bf16(a1k0, b0k0, acc[1][0], 0, 0, 0);
        acc[1][1] = __builtin_amdgcn_mfma_f32_16x16x32_bf16(a1k0, b1k0, acc[1][1], 0, 0, 0);
        acc[0][0] = __builtin_amdgcn_mfma_f32_16x16x32_bf16(a0k1, b0k1, acc[0][0], 0, 0, 0);
        acc[0][1] = __builtin_amdgcn_mfma_f32_16x16x32_bf16(a0k1, b1k1, acc[0][1], 0, 0, 0);
        acc[1][0] = __builtin_amdgcn_mfma_f32_16x16x32_bf16(a1k1, b0k1, acc[1][0], 0, 0, 0);
        acc[1][1] = __builtin_amdgcn_mfma_f32_16x16x32_bf16(a1k1, b1k1, acc[1][1], 0, 0, 0);
        __builtin_amdgcn_s_setprio(0);
        __builtin_amdgcn_s_barrier();

        // ===== phase 1: (mh=0, nh=1) — reload B-half1
        b0k0 = RD_B(2, 0); b0k1 = RD_B(2, 1);
        b1k0 = RD_B(3, 0); b1k1 = RD_B(3, 1);
        if (stg) { STAGE_A(pa2, t + 2, 2); STAGE_A(pa2, t + 2, 3); }
        __builtin_amdgcn_s_barrier();
        __builtin_amdgcn_s_setprio(1);
        acc[0][2] = __builtin_amdgcn_mfma_f32_16x16x32_bf16(a0k0, b0k0, acc[0][2], 0, 0, 0);
        acc[0][3] = __builtin_amdgcn_mfma_f32_16x16x32_bf16(a0k0, b1k0, acc[0][3], 0, 0, 0);
        acc[1][2] = __builtin_amdgcn_mfma_f32_16x16x32_bf16(a1k0, b0k0, acc[1][2], 0, 0, 0);
        acc[1][3] = __builtin_amdgcn_mfma_f32_16x16x32_bf16(a1k0, b1k0, acc[1][3], 0, 0, 0);
        acc[0][2] = __builtin_amdgcn_mfma_f32_16x16x32_bf16(a0k1, b0k1, acc[0][2], 0, 0, 0);
        acc[0][3] = __builtin_amdgcn_mfma_f32_16x16x32_bf16(a0k1, b1k1, acc[0][3], 0, 0, 0);
        acc[1][2] = __builtin_amdgcn_mfma_f32_16x16x32_bf16(a1k1, b0k1, acc[1][2], 0, 0, 0);
        acc[1][3] = __builtin_amdgcn_mfma_f32_16x16x32_bf16(a1k1, b1k1, acc[1][3], 0, 0, 0);
        __builtin_amdgcn_s_setprio(0);
        __builtin_amdgcn_s_barrier();

        // ===== phase 2: (mh=1, nh=1) — reload A-half1
        a0k0 = RD_A(2, 0); a0k1 = RD_A(2, 1);
        a1k0 = RD_A(3, 0); a1k1 = RD_A(3, 1);
        if (stg) { STAGE_B(pb2, t + 2, 0); STAGE_B(pb2, t + 2, 1); }
        __builtin_amdgcn_s_barrier();
        __builtin_amdgcn_s_setprio(1);
        acc[2][2] = __builtin_amdgcn_mfma_f32_16x16x32_bf16(a0k0, b0k0, acc[2][2], 0, 0, 0);
        acc[2][3] = __builtin_amdgcn_mfma_f32_16x16x32_bf16(a0k0, b1k0, acc[2][3], 0, 0, 0);
        acc[3][2] = __builtin_amdgcn_mfma_f32_16x16x32_bf16(a1k0, b0k0, acc[3][2], 0, 0, 0);
        acc[3][3] = __builtin_amdgcn_mfma_f32_16x16x32_bf16(a1k0, b1k0, acc[3][3], 0, 0, 0);
        acc[2][2] = __builtin_amdgcn_mfma_f32_16x16x32_bf16(a0k1, b0k1, acc[2][2], 0, 0, 0);
        acc[2][3] = __builtin_amdgcn_mfma_f32_16x16x32_bf16(a0k1, b1k1, acc[2][3], 0, 0, 0);
        acc[3][2] = __builtin_amdgcn_mfma_f32_16x16x32_bf16(a1k1, b0k1, acc[3][2], 0, 0, 0);
        acc[3][3] = __builtin_amdgcn_mfma_f32_16x16x32_bf16(a1k1, b1k1, acc[3][3], 0, 0, 0);
        __builtin_amdgcn_s_setprio(0);
        __builtin_amdgcn_s_barrier();

        // ===== phase 3: (mh=1, nh=0) — reload B-half0
        b0k0 = RD_B(0, 0); b0k1 = RD_B(0, 1);
        b1k0 = RD_B(1, 0); b1k1 = RD_B(1, 1);
        __builtin_amdgcn_s_barrier();
        __builtin_amdgcn_s_setprio(1);
        acc[2][0] = __builtin_amdgcn_mfma_f32_16x16x32_bf16(a0k0, b0k0, acc[2][0], 0, 0, 0);
        acc[2][1] = __builtin_amdgcn_mfma_f32_16x16x32_bf16(a0k0, b1k0, acc[2][1], 0, 0, 0);
        acc[3][0] = __builtin_amdgcn_mfma_f32_16x16x32_bf16(a1k0, b0k0, acc[3][0], 0, 0, 0);
        acc[3][1] = __builtin_amdgcn_mfma_f32_16x16x32_bf16(a1k0, b1k0, acc[3][1], 0, 0, 0);
        acc[2][0] = __builtin_amdgcn_mfma_f32_16x16x32_bf16(a0k1, b0k1, acc[2][0], 0, 0, 0);
        acc[2][1] = __builtin_amdgcn_mfma_f32_16x16x32_bf16(a0k1, b1k1, acc[2][1], 0, 0, 0);
        acc[3][0] = __builtin_amdgcn_mfma_f32_16x16x32_bf16(a1k1, b0k1, acc[3][0], 0, 0, 0);
        acc[3][1] = __builtin_amdgcn_mfma_f32_16x16x32_bf16(a1k1, b1k1, acc[3][1], 0, 0, 0);
        __builtin_amdgcn_s_setprio(0);

        // ===== tile boundary: counted vmcnt, single sync, rotate
        if (t < NT - 1) {
            if (stg) asm volatile("s_waitcnt vmcnt(6)" ::: "memory");
            else     asm volatile("s_waitcnt vmcnt(0)" ::: "memory");
            __builtin_amdgcn_s_barrier();
            char* ta = pa0; pa0 = pa1; pa1 = pa2; pa2 = ta;
            char* tb = pb0; pb0 = pb1; pb1 = pb2; pb2 = tb;
        }
    }

    // ---- epilogue (C/D: col = lane&15, row = (lane>>4)*4 + reg)
    if constexpr (MODE == 0) {
        float bv[4];
#pragma unroll
        for (int n = 0; n < 4; ++n) bv[n] = bias[colbase + wn * 64 + n * 16 + lo];
#pragma unroll
        for (int m = 0; m < 4; ++m)
#pragma unroll
            for (int r = 0; r < 4; ++r) {
                const int rg = rowbase + wm * 64 + m * 16 + hi * 4 + r;
                float s = 0.f;
#pragma unroll
                for (int n = 0; n < 4; ++n) {
                    const float zf = acc[m][n][r] + bv[n];
                    Zout[(size_t)rg * D_DIM + colbase + wn * 64 + n * 16 + lo] = f2b(zf);
                    s += zf * zf;
                }
                s += __shfl_xor(s, 1); s += __shfl_xor(s, 2);
                s += __shfl_xor(s, 4); s += __shfl_xor(s, 8);
                if (lo == 0) z2p_out[(size_t)(bn * 2 + wn) * B_ROWS + rg] = s;
            }
    } else {
        float p2v[4];
#pragma unroll
        for (int n = 0; n < 4; ++n) p2v[n] = p2[colbase + wn * 64 + n * 16 + lo];
#pragma unroll
        for (int m = 0; m < 4; ++m)
#pragma unroll
            for (int r = 0; r < 4; ++r) {
                const int rl = wm * 64 + m * 16 + hi * 4 + r;
                const int rg = rowbase + rl;
                const float zv = z2loc[rl];
#pragma unroll
                for (int n = 0; n < 4; ++n) {
                    const int cg = colbase + wn * 64 + n * 16 + lo;
                    if (cg < C_CLS)
                        Out[(size_t)rg * C_CLS + cg] =
                            (2.f * acc[m][n][r] - zv - p2v[n]) * (1.f / 1024.f);
                }
            }
    }
}

extern "C" void kernel_launch(void* const* d_in, const int* in_sizes, int n_in,
                              void* d_out, int out_size, void* d_ws, size_t ws_size,
                              hipStream_t stream) {
    const float* x = (const float*)d_in[0];   // [8192, 2048]
    const float* W = (const float*)d_in[1];   // [2048, 1024]
    const float* b = (const float*)d_in[2];   // [1024]
    const float* P = (const float*)d_in[3];   // [1000, 1024]
    float* out = (float*)d_out;               // [8192, 1000]

    char* ws = (char*)d_ws;
    unsigned short* Wt  = (unsigned short*)(ws);                        //  4 MB
    unsigned short* Pb  = (unsigned short*)(ws + (4  << 20));           //  2 MB
    unsigned short* Zb  = (unsigned short*)(ws + (6  << 20));           // 16 MB
    float*          p2  = (float*)(ws + (22 << 20) + (64 << 10));       //  4 KB
    float*          z2p = (float*)(ws + (22 << 20) + (128 << 10));      // 512 KB
    unsigned short* xb  = (unsigned short*)(ws + (23 << 20));           // 32 MB

    const unsigned lds_bytes = 3 * (256 * 64 * 2 + 128 * 64 * 2) + 1024; // 145 KB

    k_pre<<<dim3(11264), dim3(256), 0, stream>>>(W, P, x, Wt, Pb, xb, p2);
    k_gemm8<0><<<dim3(256), dim3(512), lds_bytes, stream>>>(
        xb, Wt, b, nullptr, nullptr, Zb, z2p, nullptr);
    k_gemm8<1><<<dim3(256), dim3(512), lds_bytes, stream>>>(
        Zb, Pb, nullptr, z2p, p2, nullptr, nullptr, out);
}

// Round 8
// 74.901 us; speedup vs baseline: 1.1179x; 1.1179x over previous
//
#include <hip/hip_runtime.h>

#define B_ROWS 8192
#define IN_DIM 2048
#define D_DIM  1024
#define C_CLS  1000

typedef __attribute__((ext_vector_type(8))) short   bf16x8;
typedef __attribute__((ext_vector_type(4))) float   f32x4;

__device__ __forceinline__ unsigned short f2b(float f) {
    unsigned int u = __builtin_bit_cast(unsigned int, f);
    u = u + 0x7fffu + ((u >> 16) & 1u);   // RNE
    return (unsigned short)(u >> 16);
}
__device__ __forceinline__ unsigned cvtpk(float lo, float hi) {
    unsigned r;
    asm("v_cvt_pk_bf16_f32 %0, %1, %2" : "=v"(r) : "v"(lo), "v"(hi));
    return r;
}
__device__ __forceinline__ void g2lds16(const void* g, void* l) {
    __builtin_amdgcn_global_load_lds(
        (const __attribute__((address_space(1))) unsigned int*)g,
        (__attribute__((address_space(3))) unsigned int*)l,
        16, 0, 0);
}

// ---------------- fused prep (xb pass ELIMINATED — x is consumed f32 by gemm0):
//   blocks [0,2048):      W[2048][1024] f32 -> Wt[1024][2048] bf16 (transpose+cvt)
//   blocks [2048,3072):   prototypes -> Pb bf16 (rows >=1000 zeroed) + p2
__global__ __launch_bounds__(256) void k_pre(const float* __restrict__ W,
                                             const float* __restrict__ P,
                                             unsigned short* __restrict__ Wt,
                                             unsigned short* __restrict__ Pb,
                                             float* __restrict__ p2) {
    const int tid = threadIdx.x;
    if (blockIdx.x < 2048) {
        __shared__ float t[32][33];
        const int tx = tid & 31, ty = tid >> 5;           // 32 x 8
        const int kb = (blockIdx.x & 63) * 32;            // K (2048/32=64)
        const int nb = (blockIdx.x >> 6) * 32;            // N (1024/32=32)
#pragma unroll
        for (int j = 0; j < 4; ++j)
            t[ty + 8 * j][tx] = W[(size_t)(kb + ty + 8 * j) * D_DIM + nb + tx];
        __syncthreads();
#pragma unroll
        for (int j = 0; j < 4; ++j)
            Wt[(size_t)(nb + ty + 8 * j) * IN_DIM + kb + tx] = f2b(t[tx][ty + 8 * j]);
    } else {
        const int c = blockIdx.x - 2048;   // 0..1023
        float s = 0.f;
        if (c < C_CLS) {
            float4 v = *((const float4*)(P + (size_t)c * D_DIM) + tid);
            s = v.x * v.x + v.y * v.y + v.z * v.z + v.w * v.w;
            ushort4 h; h.x = f2b(v.x); h.y = f2b(v.y); h.z = f2b(v.z); h.w = f2b(v.w);
            *((ushort4*)(Pb + (size_t)c * D_DIM) + tid) = h;
        } else {
            ushort4 h; h.x = 0; h.y = 0; h.z = 0; h.w = 0;
            *((ushort4*)(Pb + (size_t)c * D_DIM) + tid) = h;
        }
#pragma unroll
        for (int o = 32; o > 0; o >>= 1) s += __shfl_down(s, o);
        __shared__ float red[4];
        if ((tid & 63) == 0) red[tid >> 6] = s;
        __syncthreads();
        if (tid == 0) p2[c] = red[0] + red[1] + red[2] + red[3];
    }
}

// ---------------- deep-pipelined GEMM: tile 256x128, BK=64, 512 thr (8 waves 4Mx2N)
// Free-run K-tile body (r6-validated), ONE {counted wait; barrier} per K-tile.
// MODE 0: Zb = cvt_bf16(x) @ Wt^T + bias + z2 partials.  K = 2048.
//         A reg-staged f32->bf16, COALESCED (8 lanes/row, 256B rows), pipelined
//         one tile ahead: WRITEA(t+1) waits only A(t+1) (issued last tile, via
//         implicit counted vmcnt); B prefetches stay in flight across barriers.
//         A: 2 LDS buffers, B: 3. LDS 112 KB.
// MODE 1: Out = (2*(Zb @ Pb^T) - z2 - p2)/1024.  K = 1024. Fully async, vmcnt(6).
template <int MODE>
__global__ __launch_bounds__(512, 2) void k_gemm8(
    const float* __restrict__ Axf,            // MODE0: x f32 [8192][2048]
    const unsigned short* __restrict__ Ab,    // MODE1: Zb [8192][1024]
    const unsigned short* __restrict__ Bt,    // [N][K] bf16
    const float* __restrict__ bias,
    const float* __restrict__ z2p_in,         // MODE1: [16][8192]
    const float* __restrict__ p2,
    unsigned short* __restrict__ Zout,
    float* __restrict__ z2p_out,
    float* __restrict__ Out) {
    constexpr int K  = (MODE == 0) ? IN_DIM : D_DIM;
    constexpr int NT = K / 64;
    constexpr unsigned ASZ = 256 * 64 * 2;    // 32 KB / stage
    constexpr unsigned BSZ = 128 * 64 * 2;    // 16 KB / stage
    constexpr int NA = (MODE == 0) ? 2 : 3;
    extern __shared__ char lds[];
    char* pa0 = lds;                 char* pa1 = lds + ASZ;
    char* pa2 = (MODE == 0) ? pa1 : lds + 2 * ASZ;
    char* pb0 = lds + NA * ASZ;      char* pb1 = pb0 + BSZ;  char* pb2 = pb0 + 2 * BSZ;
    float* z2loc = (float*)(lds + NA * ASZ + 3 * BSZ);       // 1 KB (MODE1)

    const int tid  = threadIdx.x;
    const int wave = tid >> 6, lane = tid & 63;
    const int lo = lane & 15, hi = lane >> 4;
    const int wm = wave >> 1, wn = wave & 1;   // 4M x 2N waves, 64x64 each

    const int swz = ((blockIdx.x & 7) << 5) + (blockIdx.x >> 3);
    const int bm = swz >> 3, bn = swz & 7;     // 32 x 8
    const int rowbase = bm * 256, colbase = bn * 128;

    const int srow   = lane >> 3;
    const int gchunk = (lane & 7) ^ (srow & 7);   // pre-XOR'd source, linear LDS dest

    auto STAGE_B = [&](char* dst, int kt, int i) {   // i 0..1 (16 segs / 8 waves)
        const int s = i * 8 + wave;
        g2lds16(Bt + (size_t)(colbase + s * 8 + srow) * K + kt * 64 + gchunk * 8,
                dst + s * 1024);
    };
    auto STAGE_A_ASY = [&](char* dst, int kt, int i) {  // i 0..3 (MODE1)
        const int s = i * 8 + wave;
        g2lds16(Ab + (size_t)(rowbase + s * 8 + srow) * K + kt * 64 + gchunk * 8,
                dst + s * 1024);
    };

    // MODE0 A reg-stage, COALESCED: 8 lanes/row; thread -> rows (i*64 + tid>>3),
    // chunk tid&7 (32B f32 -> 16B bf16). 4 rows x 2 float4 per thread.
    const int arow   = tid >> 3;     // 0..63
    const int achunk = tid & 7;
    float4 areg[8];
    auto LOADA = [&](int kt) {
#pragma unroll
        for (int i = 0; i < 4; ++i) {
            const float4* gp = (const float4*)(
                Axf + (size_t)(rowbase + i * 64 + arow) * K + kt * 64 + achunk * 8);
            areg[2 * i] = gp[0]; areg[2 * i + 1] = gp[1];
        }
    };
    auto WRITEA = [&](char* dst) {
#pragma unroll
        for (int i = 0; i < 4; ++i) {
            const int r = i * 64 + arow;
            uint4 w;
            w.x = cvtpk(areg[2 * i].x,     areg[2 * i].y);
            w.y = cvtpk(areg[2 * i].z,     areg[2 * i].w);
            w.z = cvtpk(areg[2 * i + 1].x, areg[2 * i + 1].y);
            w.w = cvtpk(areg[2 * i + 1].z, areg[2 * i + 1].w);
            *(uint4*)(dst + r * 128 + ((achunk ^ (r & 7)) << 4)) = w;
        }
    };

    f32x4 acc[4][4];
#pragma unroll
    for (int m = 0; m < 4; ++m)
#pragma unroll
        for (int n = 0; n < 4; ++n) acc[m][n] = (f32x4){0.f, 0.f, 0.f, 0.f};

    // ---- prologue
    if constexpr (MODE == 0) {
        LOADA(0);                                   // A(0) x8  (oldest in FIFO)
        STAGE_B(pb0, 0, 0); STAGE_B(pb0, 0, 1);     // B(0) x2
        STAGE_B(pb1, 1, 0); STAGE_B(pb1, 1, 1);     // B(1) x2
        WRITEA(pa0);                                // implicit wait: A(0) done
        LOADA(1);                                   // A(1) x8
        // B(0) must land; leave B(1)x2 + A(1)x8 = 10 in flight
        asm volatile("s_waitcnt vmcnt(10) lgkmcnt(0)" ::: "memory");
    } else {
        if (tid < 256) {
            float s = 0.f;
#pragma unroll
            for (int j = 0; j < 16; ++j) s += z2p_in[j * B_ROWS + rowbase + tid];
            z2loc[tid] = s;
        }
#pragma unroll
        for (int i = 0; i < 4; ++i) STAGE_A_ASY(pa0, 0, i);
        STAGE_B(pb0, 0, 0); STAGE_B(pb0, 0, 1);
#pragma unroll
        for (int i = 0; i < 4; ++i) STAGE_A_ASY(pa1, 1, i);
        STAGE_B(pb1, 1, 0); STAGE_B(pb1, 1, 1);
        asm volatile("s_waitcnt vmcnt(6) lgkmcnt(0)" ::: "memory");
    }
    __builtin_amdgcn_s_barrier();

    auto COMPUTE = [&]() {
#pragma unroll
        for (int ks = 0; ks < 2; ++ks) {
            bf16x8 af[4], bfr[4];
#pragma unroll
            for (int m = 0; m < 4; ++m) {
                const int row = wm * 64 + m * 16 + lo;
                unsigned addr = (unsigned)(row * 128 + ks * 64 + hi * 16)
                              ^ (unsigned)((lo & 7) << 4);
                af[m] = *(const bf16x8*)(pa0 + addr);
            }
#pragma unroll
            for (int n = 0; n < 4; ++n) {
                const int row = wn * 64 + n * 16 + lo;
                unsigned addr = (unsigned)(row * 128 + ks * 64 + hi * 16)
                              ^ (unsigned)((lo & 7) << 4);
                bfr[n] = *(const bf16x8*)(pb0 + addr);
            }
            __builtin_amdgcn_s_setprio(1);
#pragma unroll
            for (int m = 0; m < 4; ++m)
#pragma unroll
                for (int n = 0; n < 4; ++n)
                    acc[m][n] = __builtin_amdgcn_mfma_f32_16x16x32_bf16(
                        af[m], bfr[n], acc[m][n], 0, 0, 0);
            __builtin_amdgcn_s_setprio(0);
        }
    };

    // ---- main loop: ONE {counted wait; barrier} per K-tile, waves free-run inside
    for (int t = 0; t < NT; ++t) {
        const bool stg = (t < NT - 2);
        if (stg) {
            if constexpr (MODE == 1) {
#pragma unroll
                for (int i = 0; i < 4; ++i) STAGE_A_ASY(pa2, t + 2, i);
            }
            STAGE_B(pb2, t + 2, 0); STAGE_B(pb2, t + 2, 1);
        }
        COMPUTE();
        if (t < NT - 1) {
            if constexpr (MODE == 0) {
                // implicit counted vmcnt inside WRITEA: waits A(t+1) (issued last
                // tile, already landed) => B(t+1), older, also landed. B(t+2)
                // stays in flight across the barrier.
                WRITEA(pa1);
                if (stg) LOADA(t + 2);
                asm volatile("s_waitcnt lgkmcnt(0)" ::: "memory");
            } else {
                if (stg) asm volatile("s_waitcnt vmcnt(6)" ::: "memory");
                else     asm volatile("s_waitcnt vmcnt(0)" ::: "memory");
            }
            __builtin_amdgcn_s_barrier();
            if constexpr (MODE == 0) { char* t2 = pa0; pa0 = pa1; pa1 = t2; }
            else                     { char* t2 = pa0; pa0 = pa1; pa1 = pa2; pa2 = t2; }
            char* tb = pb0; pb0 = pb1; pb1 = pb2; pb2 = tb;
        }
    }

    // ---- epilogue (C/D: col = lane&15, row = (lane>>4)*4 + reg)
    if constexpr (MODE == 0) {
        float bv[4];
#pragma unroll
        for (int n = 0; n < 4; ++n) bv[n] = bias[colbase + wn * 64 + n * 16 + lo];
#pragma unroll
        for (int m = 0; m < 4; ++m)
#pragma unroll
            for (int r = 0; r < 4; ++r) {
                const int rg = rowbase + wm * 64 + m * 16 + hi * 4 + r;
                float s = 0.f;
#pragma unroll
                for (int n = 0; n < 4; ++n) {
                    const float zf = acc[m][n][r] + bv[n];
                    Zout[(size_t)rg * D_DIM + colbase + wn * 64 + n * 16 + lo] = f2b(zf);
                    s += zf * zf;
                }
                s += __shfl_xor(s, 1); s += __shfl_xor(s, 2);
                s += __shfl_xor(s, 4); s += __shfl_xor(s, 8);
                if (lo == 0) z2p_out[(size_t)(bn * 2 + wn) * B_ROWS + rg] = s;
            }
    } else {
        float p2v[4];
#pragma unroll
        for (int n = 0; n < 4; ++n) p2v[n] = p2[colbase + wn * 64 + n * 16 + lo];
#pragma unroll
        for (int m = 0; m < 4; ++m)
#pragma unroll
            for (int r = 0; r < 4; ++r) {
                const int rl = wm * 64 + m * 16 + hi * 4 + r;
                const int rg = rowbase + rl;
                const float zv = z2loc[rl];
#pragma unroll
                for (int n = 0; n < 4; ++n) {
                    const int cg = colbase + wn * 64 + n * 16 + lo;
                    if (cg < C_CLS)
                        Out[(size_t)rg * C_CLS + cg] =
                            (2.f * acc[m][n][r] - zv - p2v[n]) * (1.f / 1024.f);
                }
            }
    }
}

extern "C" void kernel_launch(void* const* d_in, const int* in_sizes, int n_in,
                              void* d_out, int out_size, void* d_ws, size_t ws_size,
                              hipStream_t stream) {
    const float* x = (const float*)d_in[0];   // [8192, 2048]
    const float* W = (const float*)d_in[1];   // [2048, 1024]
    const float* b = (const float*)d_in[2];   // [1024]
    const float* P = (const float*)d_in[3];   // [1000, 1024]
    float* out = (float*)d_out;               // [8192, 1000]

    char* ws = (char*)d_ws;
    unsigned short* Wt  = (unsigned short*)(ws);                        //  4 MB
    unsigned short* Pb  = (unsigned short*)(ws + (4  << 20));           //  2 MB
    unsigned short* Zb  = (unsigned short*)(ws + (6  << 20));           // 16 MB
    float*          p2  = (float*)(ws + (22 << 20) + (64 << 10));       //  4 KB
    float*          z2p = (float*)(ws + (22 << 20) + (128 << 10));      // 512 KB

    const unsigned lds0 = 2 * (256 * 64 * 2) + 3 * (128 * 64 * 2);          // 112 KB
    const unsigned lds1 = 3 * (256 * 64 * 2) + 3 * (128 * 64 * 2) + 1024;   // 145 KB

    k_pre<<<dim3(3072), dim3(256), 0, stream>>>(W, P, Wt, Pb, p2);
    k_gemm8<0><<<dim3(256), dim3(512), lds0, stream>>>(
        x, nullptr, Wt, b, nullptr, nullptr, Zb, z2p, nullptr);
    k_gemm8<1><<<dim3(256), dim3(512), lds1, stream>>>(
        nullptr, Zb, Pb, nullptr, z2p, p2, nullptr, nullptr, out);
}